// Round 10
// baseline (184.643 us; speedup 1.0000x reference)
//
#include <hip/hip_runtime.h>

#define NTOK 65536
#define DIN 128
#define DH 256
#define DOUT 128
#define NEXP 8
#define TPB 128       // consecutive tokens per block
#define NBLK 512      // NTOK / TPB  (2 blocks per CU)
#define TAUF 5.0f
#define MCHUNK 48     // max expert-chunk rows (3 token-16-tiles)

typedef __attribute__((ext_vector_type(8))) short short8;
typedef __attribute__((ext_vector_type(4))) float f32x4;

// ---- workspace layout (bytes) ----
#define OFF_WG   0                              // 1024 f32
#define OFF_BG   4096                           // 8 f32
#define OFF_W1F  4352                           // 8*128*256 bf16 = 524288
#define OFF_W2F  (OFF_W1F + NEXP*DIN*DH*2)      // 524288

__device__ __forceinline__ unsigned short f2bf(float f) {
  union { float f; unsigned u; } v; v.f = f;
  unsigned u = v.u;
  return (unsigned short)((u + 0x7FFFu + ((u >> 16) & 1u)) >> 16);
}

// packed f32x2 -> bf16x2 (RNE), single HW instr; lo = first operand
__device__ __forceinline__ unsigned pkbf(float a, float b) {
  unsigned r;
  asm("v_cvt_pk_bf16_f32 %0, %1, %2" : "=v"(r) : "v"(a), "v"(b));
  return r;
}

// ---- kernel 1: weight conversion (blocks 0..95) + gate fuse + aux zero (block 96) ----
// W1F layout: [e][kk 4][hc 256][kl 32]; W2F layout: [e][kk 8][oc 128][kl 32]
__global__ void k_prep(const float* __restrict__ W1, const float* __restrict__ W2,
                       unsigned short* __restrict__ W1F, unsigned short* __restrict__ W2F,
                       const float* __restrict__ Wp, const float* __restrict__ bp,
                       const float* __restrict__ Ee, float* __restrict__ Wg,
                       float* __restrict__ bg, float* __restrict__ aux) {
  __shared__ float sl[8704];
  int b = blockIdx.x, t = threadIdx.x;
  if (b == 96) {
    for (int i = 0; i < 32; i++) sl[t + i * 256] = Wp[t + i * 256];
    sl[8192 + t] = Ee[t];
    sl[8448 + t] = Ee[256 + t];
    __syncthreads();
    for (int i = 0; i < 4; i++) {
      int o = t + i * 256;
      int k = o >> 3, e = o & 7;
      float s = 0.f;
      #pragma unroll 8
      for (int l = 0; l < 64; l++) s += sl[k * 64 + l] * sl[8192 + l * 8 + e];
      Wg[o] = s;
    }
    if (t < 8) {
      float s = 0.f;
      for (int l = 0; l < 64; l++) s += bp[l] * sl[8192 + l * 8 + t];
      bg[t] = s;
    }
    if (t == 255) aux[0] = 0.f;
    return;
  }
  const float* src; unsigned short* dst;
  int stride, iters, cshift;
  if (b < 32) {
    int e = b >> 2, kk = b & 3;
    src = W1 + e * (DIN * DH) + kk * 32 * DH;
    dst = W1F + e * (DIN * DH) + kk * (32 * DH);
    stride = 257; iters = 32; cshift = 8;           // 32 x 256 slab
  } else {
    int bb = b - 32;
    int e = bb >> 3, kk = bb & 7;
    src = W2 + e * (DH * DOUT) + kk * 32 * DOUT;
    dst = W2F + e * (DH * DOUT) + kk * (32 * DOUT);
    stride = 129; iters = 16; cshift = 7;           // 32 x 128 slab
  }
  int ncols_m1 = (1 << cshift) - 1;
  for (int i = 0; i < iters; i++) {
    int idx = t + i * 256;
    int r = idx >> cshift, c = idx & ncols_m1;
    sl[r * stride + c] = src[idx];
  }
  __syncthreads();
  for (int i = 0; i < iters; i++) {
    int o = t + i * 256;                            // o = hc*32 + kl
    int n = o >> 5, cc = o & 31;
    dst[o] = f2bf(sl[cc * stride + n]);
  }
}

// ---- kernel 2: FUSED gate + expert, 128 consecutive tokens/block, 2 blocks/CU.
// Phase 1: stream x (4 thr/row) -> bf16 xs + gate partial dots (pg overlaid in hs).
// Phase 2: gate finish, top-2, per-expert LDS lists (pad 16); chunk schedule.
// Phase 3: flattened chunk loop; af+bw issued together at chunk start (both L2
// trips hide under G1 MFMA); out RMW rows prefetched before G2 MFMA. First-touch
// plain store, second-touch RMW add (block-local 64KB window, barrier-ordered). ----
__global__ void __launch_bounds__(512, 4) k_fused(
    const float* __restrict__ x,
    const unsigned short* __restrict__ W1F, const unsigned short* __restrict__ W2F,
    const float* __restrict__ b1, const float* __restrict__ b2,
    const float* __restrict__ Wg, const float* __restrict__ bg,
    float* __restrict__ pout, float* __restrict__ out) {
  __shared__ __align__(16) unsigned short xs[TPB * 136];     // 34816 B
  __shared__ __align__(16) unsigned short hs[MCHUNK * 264];  // 25344 B (pg+wgl overlay)
  __shared__ unsigned short lTok[NEXP * TPB];                // 2048 B
  __shared__ float lW[NEXP * TPB];                           // 4096 B
  __shared__ int lcnt[NEXP], ncnt[NEXP];
  __shared__ int chE[32], chS[32], nch;
  __shared__ float bgl[8];
  float* pg = (float*)hs;                 // 512*8 f32 = 16 KB (phase 1/2 only)
  float* wgl = pg + 4096;                 // 1024 f32 (phase 1 only)

  int t = threadIdx.x, b = blockIdx.x;
  int w = t >> 6, lane = t & 63, q = lane >> 4, n16 = lane & 15;

  if (t < 256) *(float4*)&wgl[t * 4] = ((const float4*)Wg)[t];
  if (t < 8) { bgl[t] = bg[t]; lcnt[t] = 0; }
  __syncthreads();

  // ---- phase 1: stream x (4 thr/row) -> bf16 xs + gate partial dots ----
  {
    int row = t >> 2, qr = t & 3;
    const float4* xr = (const float4*)(x + ((size_t)b * TPB + row) * DIN + qr * 32);
    float acc[8];
    #pragma unroll
    for (int e = 0; e < 8; e++) acc[e] = 0.f;
    #pragma unroll
    for (int j = 0; j < 8; j++) {
      float4 f = xr[j];
      int c0 = qr * 32 + j * 4;
      #pragma unroll
      for (int s = 0; s < 4; s++) {
        float xv = (s == 0) ? f.x : (s == 1) ? f.y : (s == 2) ? f.z : f.w;
        float4 wa = *(const float4*)&wgl[(c0 + s) * 8];
        float4 wb = *(const float4*)&wgl[(c0 + s) * 8 + 4];
        acc[0] += xv * wa.x; acc[1] += xv * wa.y; acc[2] += xv * wa.z; acc[3] += xv * wa.w;
        acc[4] += xv * wb.x; acc[5] += xv * wb.y; acc[6] += xv * wb.z; acc[7] += xv * wb.w;
      }
      unsigned u0 = pkbf(f.x, f.y), u1 = pkbf(f.z, f.w);
      *(uint2*)(xs + row * 136 + c0) = make_uint2(u0, u1);
    }
    #pragma unroll
    for (int e = 0; e < 8; e++) pg[t * 8 + e] = acc[e];
  }
  __syncthreads();
  // ---- phase 2: gate finish, top-2, per-expert list build ----
  if (t < TPB) {
    float p[8];
    #pragma unroll
    for (int e = 0; e < 8; e++) {
      float lg = pg[(4 * t) * 8 + e] + pg[(4 * t + 1) * 8 + e] +
                 pg[(4 * t + 2) * 8 + e] + pg[(4 * t + 3) * 8 + e] + bgl[e];
      p[e] = 1.f / (1.f + expf(-lg / TAUF));
    }
    float4* pr = (float4*)(pout + ((size_t)b * TPB + t) * 8);
    float4 pa = {p[0], p[1], p[2], p[3]}, pb = {p[4], p[5], p[6], p[7]};
    pr[0] = pa; pr[1] = pb;
    int i0 = 0; float v0 = -1.f;
    #pragma unroll
    for (int e = 0; e < 8; e++) if (p[e] > v0) { v0 = p[e]; i0 = e; }
    int i1 = -1; float v1 = -1.f;
    #pragma unroll
    for (int e = 0; e < 8; e++) if (e != i0 && p[e] > v1) { v1 = p[e]; i1 = e; }
    float s = v0 + v1 + 1e-10f;
    float w0 = v0 / s, w1 = v1 / s;
    int eMin, eMax; float wMin, wMax;
    if (i0 < i1) { eMin = i0; eMax = i1; wMin = w0; wMax = w1; }
    else         { eMin = i1; eMax = i0; wMin = w1; wMax = w0; }
    int pA = atomicAdd(&lcnt[eMin], 1);
    lTok[eMin * TPB + pA] = (unsigned short)t;              // first touch: plain store
    lW[eMin * TPB + pA] = wMin;
    int pB = atomicAdd(&lcnt[eMax], 1);
    lTok[eMax * TPB + pB] = (unsigned short)(t | 0x8000);   // second touch: RMW add
    lW[eMax * TPB + pB] = wMax;
  }
  __syncthreads();
  if (t < 8) {
    int n = lcnt[t], np = (n + 15) & ~15;
    for (int i = n; i < np; i++) { lTok[t * TPB + i] = 0x4000; lW[t * TPB + i] = 0.f; }
    ncnt[t] = np;
  }
  if (t == 0) {
    int c = 0;
    for (int e = 0; e < 8; e++)
      for (int s = 0; s < ncnt[e]; s += MCHUNK) { chE[c] = e; chS[c] = s; c++; }
    nch = c;
  }
  __syncthreads();

  // ---- phase 3: flattened chunk loop ----
  const f32x4 vz = {0.f, 0.f, 0.f, 0.f};
  int NCH = nch;
  for (int ci = 0; ci < NCH; ci++) {
    int e = chE[ci], start = chS[ci];
    int mt = (min(MCHUNK, ncnt[e] - start)) >> 4;            // 1..3 token-16-tiles
    const unsigned short* W1e = W1F + e * (DIN * DH);
    const unsigned short* W2e = W2F + e * (DH * DOUT);
    // issue BOTH weight panels now; bw's L2 trip hides under G1 MFMA
    short8 af[4][2];
    #pragma unroll
    for (int kk = 0; kk < 4; kk++)
      #pragma unroll
      for (int nt = 0; nt < 2; nt++)
        af[kk][nt] = *(const short8*)(W1e + kk * 8192 + (w * 32 + nt * 16 + n16) * 32 + q * 8);
    short8 bw[8];
    #pragma unroll
    for (int kk = 0; kk < 8; kk++)
      bw[kk] = *(const short8*)(W2e + kk * 4096 + (w * 16 + n16) * 32 + q * 8);
    float4 b1f[2];
    #pragma unroll
    for (int nt = 0; nt < 2; nt++)
      b1f[nt] = *(const float4*)(b1 + e * DH + w * 32 + nt * 16 + q * 4);
    float4 b2f = *(const float4*)(b2 + e * DOUT + w * 16 + q * 4);
    // ---- G1: hs[tok][hcol] = w * relu(X@W1 + b1); wave w -> hcols [w*32,+32) ----
    #pragma unroll
    for (int tc = 0; tc < 3; tc++) {
      if (tc < mt) {
        int ce = e * TPB + start + tc * 16 + n16;
        int xrow = lTok[ce] & 0x3FF;
        float wv = lW[ce];
        short8 bx[4];
        #pragma unroll
        for (int kk = 0; kk < 4; kk++)
          bx[kk] = *(const short8*)(xs + xrow * 136 + kk * 32 + q * 8);
        f32x4 a1[2]; a1[0] = vz; a1[1] = vz;
        #pragma unroll
        for (int kk = 0; kk < 4; kk++)
          #pragma unroll
          for (int nt = 0; nt < 2; nt++)
            a1[nt] = __builtin_amdgcn_mfma_f32_16x16x32_bf16(af[kk][nt], bx[kk], a1[nt], 0, 0, 0);
        #pragma unroll
        for (int nt = 0; nt < 2; nt++) {
          unsigned u0 = pkbf(fmaxf(a1[nt][0] + b1f[nt].x, 0.f) * wv,
                             fmaxf(a1[nt][1] + b1f[nt].y, 0.f) * wv);
          unsigned u1 = pkbf(fmaxf(a1[nt][2] + b1f[nt].z, 0.f) * wv,
                             fmaxf(a1[nt][3] + b1f[nt].w, 0.f) * wv);
          *(uint2*)(hs + (tc * 16 + n16) * 264 + w * 32 + nt * 16 + q * 4) = make_uint2(u0, u1);
        }
      }
    }
    __syncthreads();                                      // hs ready
    // ---- G2: D[row=oc][col=token]; wave w -> ocols [w*16,+16), K=256 ----
    unsigned ent[3]; float4 oldv[3]; float wv2[3]; float* pp[3];
    #pragma unroll
    for (int tc = 0; tc < 3; tc++) {
      if (tc < mt) {
        int ce = e * TPB + start + tc * 16 + n16;
        ent[tc] = lTok[ce];
        wv2[tc] = lW[ce];
        pp[tc] = out + ((size_t)b * TPB + (ent[tc] & 0x3FF)) * DOUT + w * 16 + q * 4;
        if (!(ent[tc] & 0x4000)) oldv[tc] = *(const float4*)pp[tc];   // RMW prefetch
      }
    }
    #pragma unroll
    for (int tc = 0; tc < 3; tc++) {
      if (tc < mt) {
        short8 ah[8];
        #pragma unroll
        for (int kk = 0; kk < 8; kk++)
          ah[kk] = *(const short8*)(hs + (tc * 16 + n16) * 264 + kk * 32 + q * 8);
        f32x4 a2 = vz;
        #pragma unroll
        for (int kk = 0; kk < 8; kk++)
          a2 = __builtin_amdgcn_mfma_f32_16x16x32_bf16(bw[kk], ah[kk], a2, 0, 0, 0);
        if (!(ent[tc] & 0x4000)) {
          float wv = wv2[tc];
          float4 v;
          v.x = a2[0] + wv * b2f.x; v.y = a2[1] + wv * b2f.y;
          v.z = a2[2] + wv * b2f.z; v.w = a2[3] + wv * b2f.w;
          if (ent[tc] & 0x8000) {                           // second touch: add prior
            v.x += oldv[tc].x; v.y += oldv[tc].y; v.z += oldv[tc].z; v.w += oldv[tc].w;
          }
          *(float4*)pp[tc] = v;
        }
      }
    }
    __syncthreads();                                      // stores drained before hs reuse
  }
}

extern "C" void kernel_launch(void* const* d_in, const int* in_sizes, int n_in,
                              void* d_out, int out_size, void* d_ws, size_t ws_size,
                              hipStream_t stream) {
  const float* x  = (const float*)d_in[0];
  const float* Wp = (const float*)d_in[1];
  const float* bp = (const float*)d_in[2];
  const float* Ee = (const float*)d_in[3];
  const float* W1 = (const float*)d_in[4];
  const float* b1 = (const float*)d_in[5];
  const float* W2 = (const float*)d_in[6];
  const float* b2 = (const float*)d_in[7];
  float* out = (float*)d_out;
  char* ws = (char*)d_ws;
  float* Wg = (float*)(ws + OFF_WG);
  float* bg = (float*)(ws + OFF_BG);
  unsigned short* W1F = (unsigned short*)(ws + OFF_W1F);
  unsigned short* W2F = (unsigned short*)(ws + OFF_W2F);
  float* aux = out + (size_t)NTOK * DOUT;     // scalar output
  float* pout = aux + 1;                      // p_open [N,8]

  k_prep<<<97, 256, 0, stream>>>(W1, W2, W1F, W2F, Wp, bp, Ee, Wg, bg, aux);
  k_fused<<<NBLK, 512, 0, stream>>>(x, W1F, W2F, b1, b2, Wg, bg, pout, out);
}